// Round 6
// baseline (1437.035 us; speedup 1.0000x reference)
//
#include <hip/hip_runtime.h>

#define NN 200000
#define NE 400000
#define DD 128
#define NL 5
#define AV 100
#define BV 10
#define EPSV 1e-5f
#define SCAN_BLKS 196   // ceil(NN/1024)

typedef short s8v __attribute__((ext_vector_type(8)));   // 8 bf16 (4 VGPRs)
typedef float f4v __attribute__((ext_vector_type(4)));   // 4 fp32 acc

__device__ __forceinline__ ushort f2bf(float f) {        // RNE float->bf16
  uint u = __float_as_uint(f);
  u += 0x7FFFu + ((u >> 16) & 1u);
  return (ushort)(u >> 16);
}

// ---------- encode: h = sum of atom embeddings; out(fp32) = h; hbuf(bf16) = h ----------
__global__ __launch_bounds__(256) void k_encode(const int* __restrict__ x,
    const float* __restrict__ at, ushort* __restrict__ hbuf, float* __restrict__ out) {
  int idx = blockIdx.x * 256 + threadIdx.x;       // N*D/2 threads exact
  int n = idx >> 6, dp = idx & 63;                // wave = one node -> x row broadcast
  const int* xr = x + n * 9;
  float s0 = 0.f, s1 = 0.f;
#pragma unroll
  for (int c = 0; c < 9; ++c) {
    float2 v = *(const float2*)&at[(c * AV + xr[c]) * DD + dp * 2];
    s0 += v.x; s1 += v.y;
  }
  *(float2*)&out[idx * 2] = make_float2(s0, s1);
  ((uint*)hbuf)[idx] = (uint)f2bf(s0) | ((uint)f2bf(s1) << 16);
}

// ---------- degree ----------
__global__ __launch_bounds__(256) void k_deg_init(float* __restrict__ deg,
                                                  int* __restrict__ cnt) {
  int i = blockIdx.x * 256 + threadIdx.x;
  if (i < NN) { deg[i] = 1.0f; cnt[i] = 0; }
}

__global__ __launch_bounds__(256) void k_deg_count(const int* __restrict__ ei,
    float* __restrict__ deg, int* __restrict__ cnt) {
  int e = blockIdx.x * 256 + threadIdx.x;
  if (e < NE) {
    atomicAdd(&deg[ei[e]], 1.0f);
    atomicAdd(&cnt[ei[NE + e]], 1);
  }
}

__global__ __launch_bounds__(256) void k_deg_fin(const float* __restrict__ deg,
    float* __restrict__ dis, float* __restrict__ invd) {
  int i = blockIdx.x * 256 + threadIdx.x;
  if (i < NN) {
    float dg = deg[i];
    dis[i] = rsqrtf(dg);
    invd[i] = 1.0f / dg;
  }
}

// ---------- exclusive scan of cnt -> off ----------
__global__ __launch_bounds__(256) void k_scan1(const int* __restrict__ cnt,
    int* __restrict__ off, int* __restrict__ bsum) {
  __shared__ int s[256];
  int t = threadIdx.x;
  int base = blockIdx.x * 1024 + t * 4;
  int c0 = (base + 0 < NN) ? cnt[base + 0] : 0;
  int c1 = (base + 1 < NN) ? cnt[base + 1] : 0;
  int c2 = (base + 2 < NN) ? cnt[base + 2] : 0;
  int c3 = (base + 3 < NN) ? cnt[base + 3] : 0;
  int tsum = c0 + c1 + c2 + c3;
  s[t] = tsum;
  __syncthreads();
  for (int o = 1; o < 256; o <<= 1) {
    int v = (t >= o) ? s[t - o] : 0;
    __syncthreads();
    s[t] += v;
    __syncthreads();
  }
  int excl = s[t] - tsum;
  if (base + 0 < NN) off[base + 0] = excl;
  if (base + 1 < NN) off[base + 1] = excl + c0;
  if (base + 2 < NN) off[base + 2] = excl + c0 + c1;
  if (base + 3 < NN) off[base + 3] = excl + c0 + c1 + c2;
  if (t == 255) bsum[blockIdx.x] = s[255];
}

__global__ __launch_bounds__(256) void k_scan2(const int* __restrict__ bsum,
    int* __restrict__ bbase) {
  __shared__ int s[256];
  int t = threadIdx.x;
  int v0 = (t < SCAN_BLKS) ? bsum[t] : 0;
  s[t] = v0;
  __syncthreads();
  for (int o = 1; o < 256; o <<= 1) {
    int v = (t >= o) ? s[t - o] : 0;
    __syncthreads();
    s[t] += v;
    __syncthreads();
  }
  if (t < SCAN_BLKS) bbase[t] = s[t] - v0;
}

__global__ __launch_bounds__(256) void k_scan3(int* __restrict__ off,
    const int* __restrict__ bbase, int* __restrict__ nxt) {
  int i = blockIdx.x * 256 + threadIdx.x;
  if (i < NN) {
    int v = off[i] + bbase[i >> 10];
    off[i] = v;
    nxt[i] = v;
  }
  if (i == 0) off[NN] = NE;
}

// ---------- fill CSR records: {row, packed_ea, norm_bits, 0} ----------
__global__ __launch_bounds__(256) void k_fill(const int* __restrict__ ei,
    const int* __restrict__ ea, const float* __restrict__ dis,
    int* __restrict__ nxt, int4* __restrict__ recs) {
  int e = blockIdx.x * 256 + threadIdx.x;
  if (e >= NE) return;
  int r = ei[e], c = ei[NE + e];
  int pa = ea[e * 3 + 0] + ea[e * 3 + 1] * 10 + ea[e * 3 + 2] * 100;
  float nr = dis[r] * dis[c];
  int pos = atomicAdd(&nxt[c], 1);
  recs[pos] = make_int4(r, pa, __float_as_int(nr), 0);
}

// ---------- combined bond table (fp32): btc[pa][d] ----------
__global__ __launch_bounds__(256) void k_btc(const float* __restrict__ bt,
    float* __restrict__ btc) {
  int idx = blockIdx.x * 256 + threadIdx.x;       // 1000*128 exact
  int p = idx >> 7, d = idx & 127;
  int a = p % 10, b = (p / 10) % 10, c = p / 100;
  btc[idx] = bt[(0 * BV + a) * DD + d] + bt[(1 * BV + b) * DD + d]
           + bt[(2 * BV + c) * DD + d];
}

// ---------- W -> bf16 ----------
__global__ __launch_bounds__(256) void k_wconv(const float* __restrict__ W,
    ushort* __restrict__ Wbf) {
  int i = blockIdx.x * 256 + threadIdx.x;         // 5*128*128 exact
  Wbf[i] = f2bf(W[i]);
}

// ---------- MFMA GEMM: hl(fp32) = A' @ Wl^T + bl ----------
// mode0: A' = hbuf (bf16).  mode1: A' = relu(pre*scale+shift) (fp32->bf16), fused out += A'.
// Per block: 128 nodes, 4 waves x 32 nodes. Fragments direct from global (no LDS).
__global__ __launch_bounds__(256) void k_gemm(const ushort* __restrict__ srcbf,
    const float* __restrict__ srcf, const ushort* __restrict__ Wbf,
    const float* __restrict__ bl, const float* __restrict__ scale,
    const float* __restrict__ shift, float* __restrict__ outacc,
    float* __restrict__ hl, int mode) {
  int t = threadIdx.x;
  int lane = t & 63, wave = t >> 6;
  int col = lane & 15, quad = lane >> 4;
  int nb = blockIdx.x * 128 + wave * 32;
  int r0 = nb + col, r1 = nb + 16 + col;
  bool v0 = r0 < NN, v1 = r1 < NN;
  long a0off = (long)(v0 ? r0 : NN - 1) * DD;
  long a1off = (long)(v1 ? r1 : NN - 1) * DD;

  f4v acc[2][8];
#pragma unroll
  for (int i = 0; i < 2; ++i)
#pragma unroll
    for (int j = 0; j < 8; ++j) acc[i][j] = (f4v)0.f;

#pragma unroll 1
  for (int ks = 0; ks < 4; ++ks) {
    int k0 = ks * 32 + quad * 8;                  // A[m=col][k=quad*8+j]
    s8v a0, a1;
    if (mode == 0) {
      a0 = *(const s8v*)&srcbf[a0off + k0];
      a1 = *(const s8v*)&srcbf[a1off + k0];
    } else {
      float4 sc0 = *(const float4*)&scale[k0];
      float4 sc1 = *(const float4*)&scale[k0 + 4];
      float4 sh0 = *(const float4*)&shift[k0];
      float4 sh1 = *(const float4*)&shift[k0 + 4];
      float scv[8] = {sc0.x, sc0.y, sc0.z, sc0.w, sc1.x, sc1.y, sc1.z, sc1.w};
      float shv[8] = {sh0.x, sh0.y, sh0.z, sh0.w, sh1.x, sh1.y, sh1.z, sh1.w};
      float4 p0 = *(const float4*)&srcf[a0off + k0];
      float4 p1 = *(const float4*)&srcf[a0off + k0 + 4];
      float w[8] = {p0.x, p0.y, p0.z, p0.w, p1.x, p1.y, p1.z, p1.w};
#pragma unroll
      for (int j = 0; j < 8; ++j) w[j] = fmaxf(w[j] * scv[j] + shv[j], 0.f);
      if (v0) {
        float4 o0 = *(const float4*)&outacc[a0off + k0];
        float4 o1 = *(const float4*)&outacc[a0off + k0 + 4];
        o0.x += w[0]; o0.y += w[1]; o0.z += w[2]; o0.w += w[3];
        o1.x += w[4]; o1.y += w[5]; o1.z += w[6]; o1.w += w[7];
        *(float4*)&outacc[a0off + k0] = o0;
        *(float4*)&outacc[a0off + k0 + 4] = o1;
      }
#pragma unroll
      for (int j = 0; j < 8; ++j) a0[j] = (short)f2bf(w[j]);
      p0 = *(const float4*)&srcf[a1off + k0];
      p1 = *(const float4*)&srcf[a1off + k0 + 4];
      float u[8] = {p0.x, p0.y, p0.z, p0.w, p1.x, p1.y, p1.z, p1.w};
#pragma unroll
      for (int j = 0; j < 8; ++j) u[j] = fmaxf(u[j] * scv[j] + shv[j], 0.f);
      if (v1) {
        float4 o0 = *(const float4*)&outacc[a1off + k0];
        float4 o1 = *(const float4*)&outacc[a1off + k0 + 4];
        o0.x += u[0]; o0.y += u[1]; o0.z += u[2]; o0.w += u[3];
        o1.x += u[4]; o1.y += u[5]; o1.z += u[6]; o1.w += u[7];
        *(float4*)&outacc[a1off + k0] = o0;
        *(float4*)&outacc[a1off + k0 + 4] = o1;
      }
#pragma unroll
      for (int j = 0; j < 8; ++j) a1[j] = (short)f2bf(u[j]);
    }
#pragma unroll
    for (int j = 0; j < 8; ++j) {                 // B[k][n=col] for out-tile j = W[j*16+col][k]
      s8v bf = *(const s8v*)&Wbf[(j * 16 + col) * DD + k0];
      acc[0][j] = __builtin_amdgcn_mfma_f32_16x16x32_bf16(a0, bf, acc[0][j], 0, 0, 0);
      acc[1][j] = __builtin_amdgcn_mfma_f32_16x16x32_bf16(a1, bf, acc[1][j], 0, 0, 0);
    }
  }

  float bb[8];
#pragma unroll
  for (int j = 0; j < 8; ++j) bb[j] = bl[j * 16 + col];
#pragma unroll
  for (int i = 0; i < 2; ++i) {
    int rowb = nb + i * 16 + quad * 4;            // D: col=lane&15, row=quad*4+reg
#pragma unroll
    for (int r = 0; r < 4; ++r) {
      int n = rowb + r;
      if (n < NN) {
#pragma unroll
        for (int j = 0; j < 8; ++j)
          hl[(long)n * DD + j * 16 + col] = acc[i][j][r] + bb[j];
      }
    }
  }
}

// ---------- gather-aggregate + self term + BN partials ----------
// Half-wave (32 lanes) owns one node, float4/lane = full 512B row.
// 64 nodes/block (3125 blocks -> no grid occupancy ceiling). off[] staged in LDS.
// Edge loop unrolled x4 with clamped loads + zero-masked norm: 4 recs loads then
// 4 hl gathers in flight per half-wave (4x MLP); clamped duplicates hit L1.
__global__ __launch_bounds__(256) void k_aggregate(const float* __restrict__ hl,
    const int* __restrict__ off, const int4* __restrict__ recs,
    const float* __restrict__ btc, const float* __restrict__ rootl,
    const float* __restrict__ invd, float* __restrict__ pre,
    float* __restrict__ gsum, float* __restrict__ gss) {
  __shared__ float4 redS[256], redQ[256];
  __shared__ int soff[65];
  int t = threadIdx.x;
  int ql = t & 31;                                 // lane within half-wave
  int hh = t >> 5;                                 // half-slot 0..7
  int d0 = ql * 4;
  int n0 = blockIdx.x * 64;                        // 3125 blocks * 64 = NN exact
  if (t < 65) soff[t] = off[n0 + t];
  __syncthreads();
  float4 rt = *(const float4*)&rootl[d0];
  float4 s = make_float4(0.f, 0.f, 0.f, 0.f);
  float4 q = make_float4(0.f, 0.f, 0.f, 0.f);
#pragma unroll 1
  for (int i = 0; i < 8; ++i) {
    int j = hh + i * 8;                            // node index within block
    int n = n0 + j;
    int e0 = soff[j], e1 = soff[j + 1];
    float4 acc = make_float4(0.f, 0.f, 0.f, 0.f);
#pragma unroll 1
    for (int e = e0; e < e1; e += 4) {
      int eL = e1 - 1;
      int4 rc0 = recs[e];
      int4 rc1 = recs[min(e + 1, eL)];
      int4 rc2 = recs[min(e + 2, eL)];
      int4 rc3 = recs[min(e + 3, eL)];
      float4 h0 = *(const float4*)&hl[(long)rc0.x * DD + d0];
      float4 h1 = *(const float4*)&hl[(long)rc1.x * DD + d0];
      float4 h2 = *(const float4*)&hl[(long)rc2.x * DD + d0];
      float4 h3 = *(const float4*)&hl[(long)rc3.x * DD + d0];
      float4 b0 = *(const float4*)&btc[rc0.y * DD + d0];
      float4 b1 = *(const float4*)&btc[rc1.y * DD + d0];
      float4 b2 = *(const float4*)&btc[rc2.y * DD + d0];
      float4 b3 = *(const float4*)&btc[rc3.y * DD + d0];
      float n0f = __int_as_float(rc0.z);
      float n1f = (e + 1 < e1) ? __int_as_float(rc1.z) : 0.f;
      float n2f = (e + 2 < e1) ? __int_as_float(rc2.z) : 0.f;
      float n3f = (e + 3 < e1) ? __int_as_float(rc3.z) : 0.f;
      acc.x += fmaxf(h0.x + b0.x, 0.f) * n0f;
      acc.y += fmaxf(h0.y + b0.y, 0.f) * n0f;
      acc.z += fmaxf(h0.z + b0.z, 0.f) * n0f;
      acc.w += fmaxf(h0.w + b0.w, 0.f) * n0f;
      acc.x += fmaxf(h1.x + b1.x, 0.f) * n1f;
      acc.y += fmaxf(h1.y + b1.y, 0.f) * n1f;
      acc.z += fmaxf(h1.z + b1.z, 0.f) * n1f;
      acc.w += fmaxf(h1.w + b1.w, 0.f) * n1f;
      acc.x += fmaxf(h2.x + b2.x, 0.f) * n2f;
      acc.y += fmaxf(h2.y + b2.y, 0.f) * n2f;
      acc.z += fmaxf(h2.z + b2.z, 0.f) * n2f;
      acc.w += fmaxf(h2.w + b2.w, 0.f) * n2f;
      acc.x += fmaxf(h3.x + b3.x, 0.f) * n3f;
      acc.y += fmaxf(h3.y + b3.y, 0.f) * n3f;
      acc.z += fmaxf(h3.z + b3.z, 0.f) * n3f;
      acc.w += fmaxf(h3.w + b3.w, 0.f) * n3f;
    }
    float4 sv = *(const float4*)&hl[(long)n * DD + d0];
    float iv = invd[n];
    float4 p;
    p.x = acc.x + fmaxf(sv.x + rt.x, 0.f) * iv;
    p.y = acc.y + fmaxf(sv.y + rt.y, 0.f) * iv;
    p.z = acc.z + fmaxf(sv.z + rt.z, 0.f) * iv;
    p.w = acc.w + fmaxf(sv.w + rt.w, 0.f) * iv;
    *(float4*)&pre[(long)n * DD + d0] = p;
    s.x += p.x; s.y += p.y; s.z += p.z; s.w += p.w;
    q.x += p.x * p.x; q.y += p.y * p.y; q.z += p.z * p.z; q.w += p.w * p.w;
  }
  redS[t] = s; redQ[t] = q;
  __syncthreads();
  if (t < 128) {
    int d = t, qq = d >> 2, c = d & 3;
    float S = 0.f, Q = 0.f;
#pragma unroll
    for (int h = 0; h < 8; ++h) {
      S += ((const float*)&redS[h * 32 + qq])[c];
      Q += ((const float*)&redQ[h * 32 + qq])[c];
    }
    atomicAdd(&gsum[d], S);
    atomicAdd(&gss[d], Q);
  }
}

__global__ void k_bnfin(const float* __restrict__ gsum, const float* __restrict__ gss,
    const float* __restrict__ gl, const float* __restrict__ bl,
    float* __restrict__ scale, float* __restrict__ shift) {
  int d = threadIdx.x;
  float m = gsum[d] * (1.0f / NN);
  float v = gss[d] * (1.0f / NN) - m * m;
  float sc = gl[d] * rsqrtf(v + EPSV);
  scale[d] = sc;
  shift[d] = bl[d] - m * sc;
}

// ---------- final layer apply (no relu): out += pre*scale + shift ----------
__global__ __launch_bounds__(256) void k_apply_final(const float* __restrict__ pre,
    const float* __restrict__ scale, const float* __restrict__ shift,
    float* __restrict__ out) {
  int idx = blockIdx.x * 256 + threadIdx.x;       // N*D/2 exact
  int dp = idx & 63;
  float2 pv = *(const float2*)&pre[idx * 2];
  float2 o = *(const float2*)&out[idx * 2];
  o.x += pv.x * scale[dp * 2] + shift[dp * 2];
  o.y += pv.y * scale[dp * 2 + 1] + shift[dp * 2 + 1];
  *(float2*)&out[idx * 2] = o;
}

extern "C" void kernel_launch(void* const* d_in, const int* in_sizes, int n_in,
                              void* d_out, int out_size, void* d_ws, size_t ws_size,
                              hipStream_t stream) {
  const int*   x     = (const int*)d_in[0];
  const int*   ei    = (const int*)d_in[1];
  const int*   ea    = (const int*)d_in[2];
  const float* at    = (const float*)d_in[3];
  const float* bt    = (const float*)d_in[4];
  const float* W     = (const float*)d_in[5];
  const float* b     = (const float*)d_in[6];
  const float* root  = (const float*)d_in[7];
  const float* gamma = (const float*)d_in[8];
  const float* beta  = (const float*)d_in[9];
  float* out = (float*)d_out;

  char* ws = (char*)d_ws;
  size_t ND = (size_t)NN * DD;
  float*  hl   = (float*)ws;                        // ND fp32
  float*  pre  = hl + ND;                           // ND fp32
  ushort* hbuf = (ushort*)(pre + ND);               // ND bf16
  int4*   recs = (int4*)(hbuf + ND);                // NE * 16B (offset mult of 16B)
  ushort* Wbf  = (ushort*)(recs + NE);              // 5*128*128 bf16
  float*  btc  = (float*)(Wbf + NL * DD * DD);      // 1000*128 fp32
  float*  deg  = btc + 1000 * DD;                   // N
  float*  dis  = deg + NN;                          // N
  float*  invd = dis + NN;                          // N
  int*    cnt  = (int*)(invd + NN);                 // N
  int*    offa = cnt + NN;                          // N+1 (+3 pad)
  int*    nxt  = offa + NN + 4;                     // N
  int*    bsum = nxt + NN;                          // 256
  int*    bbase= bsum + 256;                        // 256
  float*  gsum = (float*)(bbase + 256);             // D
  float*  gss  = gsum + DD;                         // D
  float*  scaleb = gss + DD;                        // D
  float*  shiftb = scaleb + DD;                     // D

  // ---- precompute ----
  k_deg_init<<<(NN + 255) / 256, 256, 0, stream>>>(deg, cnt);
  k_deg_count<<<(NE + 255) / 256, 256, 0, stream>>>(ei, deg, cnt);
  k_deg_fin<<<(NN + 255) / 256, 256, 0, stream>>>(deg, dis, invd);
  k_scan1<<<SCAN_BLKS, 256, 0, stream>>>(cnt, offa, bsum);
  k_scan2<<<1, 256, 0, stream>>>(bsum, bbase);
  k_scan3<<<(NN + 255) / 256, 256, 0, stream>>>(offa, bbase, nxt);
  k_fill<<<(NE + 255) / 256, 256, 0, stream>>>(ei, ea, dis, nxt, recs);
  k_btc<<<1000 * DD / 256, 256, 0, stream>>>(bt, btc);
  k_wconv<<<NL * DD * DD / 256, 256, 0, stream>>>(W, Wbf);
  k_encode<<<(int)(ND / 2 / 256), 256, 0, stream>>>(x, at, hbuf, out);

  // ---- layers ----
  for (int l = 0; l < NL; ++l) {
    hipMemsetAsync(gsum, 0, 2 * DD * sizeof(float), stream);
    k_gemm<<<(NN + 127) / 128, 256, 0, stream>>>(
        hbuf, pre, Wbf + (size_t)l * DD * DD, b + l * DD,
        scaleb, shiftb, out, hl, (l == 0) ? 0 : 1);
    k_aggregate<<<NN / 64, 256, 0, stream>>>(hl, offa, recs, btc,
        root + l * DD, invd, pre, gsum, gss);
    k_bnfin<<<1, DD, 0, stream>>>(gsum, gss, gamma + l * DD, beta + l * DD,
                                  scaleb, shiftb);
  }
  k_apply_final<<<(int)(ND / 2 / 256), 256, 0, stream>>>(pre, scaleb, shiftb, out);
}